// Round 15
// baseline (1870.725 us; speedup 1.0000x reference)
//
#include <hip/hip_runtime.h>
#include <cstdint>
#include <cstddef>

// SNN_53618371723788: 2-layer SLSTM, B=65536, T=24, H=64, fp32.
// setup: pack Whh1/Wih2 into global float4 per-lane layout (P1G/PihG, 64 KB
//        each, L2-hot, coalesced) in d_ws.
// Pass 1: layer-1 recurrence; dense m-loop split LDS(m<32)/global(m>=32).
// Pass 2: layer-2; dense hh from LDS, sparse ih from GLOBAL (VMEM pipe).
//
// R15: move LDS traffic to the parallel VMEM pipe. Model (fits all 14 rounds):
// both passes are LDS-data-pipe-bound (~95%): ds_read_b128 moves 1024 B =
// ~12 cyc/CU; pass2 = (128 dense + ~104 sparse) per-lane b128 + 128 broadcast
// = ~3280 cyc/wave/t -> 1050 us predicted vs 1100 measured; pass1 640 vs 650.
// R14 (pk_fma, -50% VALU) was neutral and R13 (NB=16, -50% LDS/batch, but 8
// waves) regressed -- consistent only with this model. Arithmetic orders
// unchanged -> bit-exact.

#define BB 65536
#define TT 24
#define NB 8  // batch elements per wave (two halves of 4)

typedef float pf2 __attribute__((ext_vector_type(2)));

// acc.lo += s.lo * w.lo ; acc.hi += s.hi * w.lo   (w splat = LOW half)
__device__ __forceinline__ void pk_fma_wlo(pf2& acc, pf2 s, pf2 w) {
  asm("v_pk_fma_f32 %0, %1, %2, %0 op_sel:[0,0,0] op_sel_hi:[1,0,1]"
      : "+v"(acc) : "v"(s), "v"(w));
}
// acc.lo += s.lo * w.hi ; acc.hi += s.hi * w.hi   (w splat = HIGH half)
__device__ __forceinline__ void pk_fma_whi(pf2& acc, pf2 s, pf2 w) {
  asm("v_pk_fma_f32 %0, %1, %2, %0 op_sel:[0,1,0] op_sel_hi:[1,1,1]"
      : "+v"(acc) : "v"(s), "v"(w));
}

__device__ __forceinline__ float bcastf(float v, int l) {
  return __int_as_float(__builtin_amdgcn_readlane(__float_as_int(v), l));
}
__device__ __forceinline__ float sigm(float v) {
  return __fdividef(1.0f, 1.0f + __expf(-v));
}
__device__ __forceinline__ float tanh_fast(float v) {
  return fmaf(-2.0f, __fdividef(1.0f, __expf(2.0f * v) + 1.0f), 1.0f);
}
__device__ __forceinline__ float wsum(float v) {
#pragma unroll
  for (int o = 32; o > 0; o >>= 1) v += __shfl_xor(v, o);
  return v;
}

// Pack W[256][64] (row q*64+j, col m) -> G[m*64+j] = float4 over q.
__global__ void snn_setup(const float* __restrict__ Whh1,
                          const float* __restrict__ Wih2,
                          float* __restrict__ P1G, float* __restrict__ PihG) {
  int idx = blockIdx.x * blockDim.x + threadIdx.x;
  if (idx < 16384) {
    int k = idx >> 6, m = idx & 63;  // k = q*64 + j
    int q = k >> 6, j = k & 63;
    P1G[(m * 64 + j) * 4 + q] = Whh1[idx];
    PihG[(m * 64 + j) * 4 + q] = Wih2[idx];
  }
}

__global__ __launch_bounds__(512) void snn_pass1(
    const float* __restrict__ x, const float* __restrict__ Wih1,
    const float* __restrict__ Whh1, const float* __restrict__ bih1,
    const float* __restrict__ bhh1, const float* __restrict__ thr1p,
    const float4* __restrict__ P1G,
    unsigned long long* __restrict__ spk_out, float* __restrict__ mem1_out) {
  __shared__ float4 P1[32][64];     // 32 KB: m = 0..31 only (m>=32 from P1G)
  __shared__ float stM[8][64][NB];  // 16 KB -> 48 KB total
  int tid = threadIdx.x;
  for (int idx = tid; idx < 16384; idx += 512) {
    int k = idx >> 6, m = idx & 63;
    if (m < 32) ((float*)&P1[m][k & 63])[k >> 6] = Whh1[idx];
  }
  __syncthreads();
  int lane = tid & 63, wave = tid >> 6;
  int wb = (blockIdx.x * 8 + wave) * NB;  // first batch of this wave
  float thr1 = thr1p[0];
  float b1q[4], wq[4];
#pragma unroll
  for (int q = 0; q < 4; q++) {
    b1q[q] = bih1[q * 64 + lane] + bhh1[q * 64 + lane];
    wq[q] = Wih1[q * 64 + lane];
  }
  float syn[NB], mem[NB];
#pragma unroll
  for (int b = 0; b < NB; b++) { syn[b] = 0.0f; mem[b] = 0.0f; }

  for (int t = 0; t < TT; t++) {
#pragma unroll
    for (int b = 0; b < NB; b++) stM[wave][lane][b] = mem[b];
    unsigned long long myspk = 0;  // lane b keeps batch b's ballot
#pragma unroll
    for (int h = 0; h < 2; h++) {
      const int B0 = h * 4;
      pf2 a2[4][2];
#pragma unroll
      for (int p = 0; p < 2; p++) {
        float x0 = x[(wb + B0 + 2 * p) * TT + t];
        float x1 = x[(wb + B0 + 2 * p + 1) * TT + t];
#pragma unroll
        for (int q = 0; q < 4; q++)
          a2[q][p] = (pf2){fmaf(x0, wq[q], b1q[q]), fmaf(x1, wq[q], b1q[q])};
      }
      // m = 0..31 from LDS
#pragma unroll 8
      for (int m = 0; m < 32; m++) {
        float4 w = P1[m][lane];
        float4 sa = *(const float4*)&stM[wave][m][B0];
        pf2 s01 = {sa.x, sa.y}, s23 = {sa.z, sa.w};
        pf2 wxy = {w.x, w.y}, wzw = {w.z, w.w};
        pk_fma_wlo(a2[0][0], s01, wxy);
        pk_fma_whi(a2[1][0], s01, wxy);
        pk_fma_wlo(a2[2][0], s01, wzw);
        pk_fma_whi(a2[3][0], s01, wzw);
        pk_fma_wlo(a2[0][1], s23, wxy);
        pk_fma_whi(a2[1][1], s23, wxy);
        pk_fma_wlo(a2[2][1], s23, wzw);
        pk_fma_whi(a2[3][1], s23, wzw);
      }
      // m = 32..63 from global (coalesced dwordx4, L1/L2-hot; VMEM pipe)
#pragma unroll 8
      for (int m = 32; m < 64; m++) {
        float4 w = P1G[m * 64 + lane];
        float4 sa = *(const float4*)&stM[wave][m][B0];
        pf2 s01 = {sa.x, sa.y}, s23 = {sa.z, sa.w};
        pf2 wxy = {w.x, w.y}, wzw = {w.z, w.w};
        pk_fma_wlo(a2[0][0], s01, wxy);
        pk_fma_whi(a2[1][0], s01, wxy);
        pk_fma_wlo(a2[2][0], s01, wzw);
        pk_fma_whi(a2[3][0], s01, wzw);
        pk_fma_wlo(a2[0][1], s23, wxy);
        pk_fma_whi(a2[1][1], s23, wxy);
        pk_fma_wlo(a2[2][1], s23, wzw);
        pk_fma_whi(a2[3][1], s23, wzw);
      }
#pragma unroll
      for (int j = 0; j < 4; j++) {
        int b = B0 + j, p = j >> 1;
        float aq0 = (j & 1) ? a2[0][p].y : a2[0][p].x;
        float aq1 = (j & 1) ? a2[1][p].y : a2[1][p].x;
        float aq2 = (j & 1) ? a2[2][p].y : a2[2][p].x;
        float aq3 = (j & 1) ? a2[3][p].y : a2[3][p].x;
        float ig = sigm(aq0), fg = sigm(aq1);
        float gg = tanh_fast(aq2), og = sigm(aq3);
        float sn = fmaf(fg, syn[b], ig * gg);
        float rst = (mem[b] > thr1) ? thr1 : 0.0f;  // reset uses OLD mem
        float mn = fmaf(og, tanh_fast(sn), -rst);
        syn[b] = sn;
        mem[b] = mn;
        unsigned long long msk = __ballot(mn > thr1);  // wave-uniform
        if (lane == b) myspk = msk;
      }
      __builtin_amdgcn_sched_barrier(0);
    }
    if (lane < NB)
      spk_out[(size_t)t * BB + wb + lane] = myspk;
  }
#pragma unroll
  for (int b = 0; b < NB; b++)
    mem1_out[(size_t)(wb + b) * 64 + lane] = mem[b];
}

__global__ __attribute__((amdgpu_waves_per_eu(4, 4))) __launch_bounds__(1024)
void snn_pass2(
    const float* __restrict__ Wih2, const float* __restrict__ Whh2,
    const float* __restrict__ bih2, const float* __restrict__ bhh2,
    const float* __restrict__ thr2p, const float* __restrict__ Wout,
    const float* __restrict__ bout, const float4* __restrict__ PihG,
    const unsigned long long* __restrict__ spk_in,
    const float* __restrict__ mem1_in, float* __restrict__ out) {
  __shared__ float4 Phh[64][64];     // 64 KB (Pih now global-only)
  __shared__ float stM[16][64][NB];  // 32 KB -> 96 KB total
  int tid = threadIdx.x;
  for (int idx = tid; idx < 16384; idx += 1024) {
    int k = idx >> 6, m = idx & 63;
    ((float*)&Phh[m][k & 63])[k >> 6] = Whh2[idx];
  }
  __syncthreads();
  int lane = tid & 63, wave = tid >> 6;
  int wb = (blockIdx.x * 16 + wave) * NB;
  float thr2 = thr2p[0];
  float b2q[4];
#pragma unroll
  for (int q = 0; q < 4; q++) b2q[q] = bih2[q * 64 + lane] + bhh2[q * 64 + lane];
  float syn[NB], mem[NB];
  unsigned sb8[NB];  // per-lane spike history of THIS lane's neuron, bit t
#pragma unroll
  for (int b = 0; b < NB; b++) { syn[b] = 0.0f; mem[b] = 0.0f; sb8[b] = 0u; }

  for (int t = 0; t < TT; t++) {
    // spike masks -> SGPR u64 (wave-uniform)
    unsigned long long mk[NB];
#pragma unroll
    for (int b = 0; b < NB; b++) {
      unsigned long long v = spk_in[(size_t)t * BB + wb + b];
      unsigned lo = __builtin_amdgcn_readfirstlane((unsigned)v);
      unsigned hi = __builtin_amdgcn_readfirstlane((unsigned)(v >> 32));
      mk[b] = ((unsigned long long)hi << 32) | (unsigned long long)lo;
    }
#pragma unroll
    for (int b = 0; b < NB; b++) stM[wave][lane][b] = mem[b];
#pragma unroll
    for (int h = 0; h < 2; h++) {
      const int B0 = h * 4;
      pf2 a2[4][2];
#pragma unroll
      for (int q = 0; q < 4; q++) {
#pragma unroll
        for (int p = 0; p < 2; p++) a2[q][p] = (pf2){b2q[q], b2q[q]};
      }
      // dense hh half: LDS weights + broadcast state, packed dual-FMA
#pragma unroll 8
      for (int m = 0; m < 64; m++) {
        float4 wh = Phh[m][lane];
        float4 sa = *(const float4*)&stM[wave][m][B0];
        pf2 s01 = {sa.x, sa.y}, s23 = {sa.z, sa.w};
        pf2 wxy = {wh.x, wh.y}, wzw = {wh.z, wh.w};
        pk_fma_wlo(a2[0][0], s01, wxy);
        pk_fma_whi(a2[1][0], s01, wxy);
        pk_fma_wlo(a2[2][0], s01, wzw);
        pk_fma_whi(a2[3][0], s01, wzw);
        pk_fma_wlo(a2[0][1], s23, wxy);
        pk_fma_whi(a2[1][1], s23, wxy);
        pk_fma_wlo(a2[2][1], s23, wzw);
        pk_fma_whi(a2[3][1], s23, wzw);
      }
      // sparse ih half: GLOBAL reads (VMEM pipe, coalesced, L2-hot),
      // 4-deep pipeline, adds ascending-bit (order preserved -> bit-exact)
#pragma unroll
      for (int j = 0; j < 4; j++) {
        int b = B0 + j, p = j >> 1;
        unsigned long long k = mk[b];
        while (__builtin_popcountll(k) >= 4) {
          int m0 = __builtin_ctzll(k); k &= k - 1;
          int m1 = __builtin_ctzll(k); k &= k - 1;
          int m2 = __builtin_ctzll(k); k &= k - 1;
          int m3 = __builtin_ctzll(k); k &= k - 1;
          float4 r0 = PihG[m0 * 64 + lane];
          float4 r1 = PihG[m1 * 64 + lane];
          float4 r2 = PihG[m2 * 64 + lane];
          float4 r3 = PihG[m3 * 64 + lane];
          if ((j & 1) == 0) {
            a2[0][p].x += r0.x; a2[1][p].x += r0.y; a2[2][p].x += r0.z; a2[3][p].x += r0.w;
            a2[0][p].x += r1.x; a2[1][p].x += r1.y; a2[2][p].x += r1.z; a2[3][p].x += r1.w;
            a2[0][p].x += r2.x; a2[1][p].x += r2.y; a2[2][p].x += r2.z; a2[3][p].x += r2.w;
            a2[0][p].x += r3.x; a2[1][p].x += r3.y; a2[2][p].x += r3.z; a2[3][p].x += r3.w;
          } else {
            a2[0][p].y += r0.x; a2[1][p].y += r0.y; a2[2][p].y += r0.z; a2[3][p].y += r0.w;
            a2[0][p].y += r1.x; a2[1][p].y += r1.y; a2[2][p].y += r1.z; a2[3][p].y += r1.w;
            a2[0][p].y += r2.x; a2[1][p].y += r2.y; a2[2][p].y += r2.z; a2[3][p].y += r2.w;
            a2[0][p].y += r3.x; a2[1][p].y += r3.y; a2[2][p].y += r3.z; a2[3][p].y += r3.w;
          }
        }
        while (k) {
          int m0 = __builtin_ctzll(k); k &= k - 1;
          float4 r0 = PihG[m0 * 64 + lane];
          if ((j & 1) == 0) {
            a2[0][p].x += r0.x; a2[1][p].x += r0.y; a2[2][p].x += r0.z; a2[3][p].x += r0.w;
          } else {
            a2[0][p].y += r0.x; a2[1][p].y += r0.y; a2[2][p].y += r0.z; a2[3][p].y += r0.w;
          }
        }
        float aq0 = (j & 1) ? a2[0][p].y : a2[0][p].x;
        float aq1 = (j & 1) ? a2[1][p].y : a2[1][p].x;
        float aq2 = (j & 1) ? a2[2][p].y : a2[2][p].x;
        float aq3 = (j & 1) ? a2[3][p].y : a2[3][p].x;
        float ig = sigm(aq0), fg = sigm(aq1);
        float gg = tanh_fast(aq2), og = sigm(aq3);
        float sn = fmaf(fg, syn[b], ig * gg);
        float rst = (mem[b] > thr2) ? thr2 : 0.0f;
        float mn = fmaf(og, tanh_fast(sn), -rst);
        syn[b] = sn;
        mem[b] = mn;
        sb8[b] |= (mn > thr2) ? (1u << t) : 0u;
      }
      __builtin_amdgcn_sched_barrier(0);
    }
  }

  // extra step: input = final mem1 (dense). Pih from global (one-shot).
  float m1[NB];
#pragma unroll
  for (int b = 0; b < NB; b++) m1[b] = mem1_in[(size_t)(wb + b) * 64 + lane];
  float acc[NB][4];
#pragma unroll
  for (int b = 0; b < NB; b++) {
#pragma unroll
    for (int q = 0; q < 4; q++) acc[b][q] = b2q[q];
  }
#pragma unroll 4
  for (int m = 0; m < 64; m++) {
    float4 wi = PihG[m * 64 + lane];
    float4 wh = Phh[m][lane];
#pragma unroll
    for (int b = 0; b < NB; b++) {
      float s1 = bcastf(m1[b], m);
      float s2 = bcastf(mem[b], m);
      acc[b][0] = fmaf(s1, wi.x, fmaf(s2, wh.x, acc[b][0]));
      acc[b][1] = fmaf(s1, wi.y, fmaf(s2, wh.y, acc[b][1]));
      acc[b][2] = fmaf(s1, wi.z, fmaf(s2, wh.z, acc[b][2]));
      acc[b][3] = fmaf(s1, wi.w, fmaf(s2, wh.w, acc[b][3]));
    }
  }
  // epilogue: replay p0/p1 accumulation (same fmaf order) from sb8 bits.
  float p0[NB], p1[NB];
#pragma unroll
  for (int b = 0; b < NB; b++) { p0[b] = 0.0f; p1[b] = 0.0f; }
#pragma unroll 4
  for (int t = 0; t < TT; t++) {
    float w0 = Wout[t * 64 + lane];
    float w1 = Wout[1664 + t * 64 + lane];
#pragma unroll
    for (int b = 0; b < NB; b++) {
      float sf = ((sb8[b] >> t) & 1u) ? 1.0f : 0.0f;
      p0[b] = fmaf(sf, w0, p0[b]);
      p1[b] = fmaf(sf, w1, p1[b]);
    }
  }
  float wA0 = Wout[1536 + lane], wA1 = Wout[1664 + 1536 + lane];  // spk2_last
  float wB0 = Wout[1600 + lane], wB1 = Wout[1664 + 1600 + lane];  // mem2 final
  float bo0 = bout[0], bo1 = bout[1];
#pragma unroll
  for (int b = 0; b < NB; b++) {
    float ig = sigm(acc[b][0]), fg = sigm(acc[b][1]);
    float gg = tanh_fast(acc[b][2]), og = sigm(acc[b][3]);
    float sn = fmaf(fg, syn[b], ig * gg);
    float rst = (mem[b] > thr2) ? thr2 : 0.0f;
    float mn = fmaf(og, tanh_fast(sn), -rst);
    float sf = (mn > thr2) ? 1.0f : 0.0f;
    p0[b] = fmaf(sf, wA0, p0[b]);
    p1[b] = fmaf(sf, wA1, p1[b]);
    p0[b] = fmaf(mn, wB0, p0[b]);
    p1[b] = fmaf(mn, wB1, p1[b]);
  }
  // cross-lane reduce; wsum result is uniform, keep own lane's value.
  float vout = 0.0f;
#pragma unroll
  for (int b = 0; b < NB; b++) {
    float r0 = wsum(p0[b]);
    float r1 = wsum(p1[b]);
    if (lane == 2 * b) vout = r0;
    if (lane == 2 * b + 1) vout = r1;
  }
  if (lane < 2 * NB)
    out[(size_t)wb * 2 + lane] = vout + ((lane & 1) ? bo1 : bo0);
}

extern "C" void kernel_launch(void* const* d_in, const int* in_sizes, int n_in,
                              void* d_out, int out_size, void* d_ws, size_t ws_size,
                              hipStream_t stream) {
  const float* x = (const float*)d_in[0];
  const float* Wih1 = (const float*)d_in[1];
  const float* Whh1 = (const float*)d_in[2];
  const float* bih1 = (const float*)d_in[3];
  const float* bhh1 = (const float*)d_in[4];
  const float* thr1 = (const float*)d_in[5];
  const float* Wih2 = (const float*)d_in[6];
  const float* Whh2 = (const float*)d_in[7];
  const float* bih2 = (const float*)d_in[8];
  const float* bhh2 = (const float*)d_in[9];
  const float* thr2 = (const float*)d_in[10];
  const float* Wout = (const float*)d_in[11];
  const float* bout = (const float*)d_in[12];

  unsigned long long* spk = (unsigned long long*)d_ws;
  float* mem1 = (float*)((char*)d_ws + (size_t)TT * BB * 8);
  float* P1G = (float*)((char*)d_ws + (size_t)TT * BB * 8 + (size_t)BB * 64 * 4);
  float* PihG = P1G + 16384;  // 64 KB each; ws total 29,491,200 B

  snn_setup<<<32, 512, 0, stream>>>(Whh1, Wih2, P1G, PihG);
  snn_pass1<<<BB / (8 * NB), 512, 0, stream>>>(x, Wih1, Whh1, bih1, bhh1, thr1,
                                               (const float4*)P1G, spk, mem1);
  snn_pass2<<<BB / (16 * NB), 1024, 0, stream>>>(Wih2, Whh2, bih2, bhh2, thr2,
                                                 Wout, bout, (const float4*)PihG,
                                                 spk, mem1, (float*)d_out);
}

// Round 16
// 1857.880 us; speedup vs baseline: 1.0069x; 1.0069x over previous
//
#include <hip/hip_runtime.h>
#include <cstdint>
#include <cstddef>

// SNN_53618371723788: 2-layer SLSTM, B=65536, T=24, H=64, fp32. FUSED.
// R16: single kernel runs both layers per timestep. Rationale: R14 (half the
// VALU) and R15 (-40% LDS ops) were both neutral -> pass2 sits at a multi-
// resource balance; the remaining cost is structural: 32 MB spk/mem1 HBM
// round-trip between passes, duplicate launches/staging, and unfillable
// latency bubbles. Fused: spike masks stay in SGPRs (ballot is uniform),
// mem1 stays in registers, layer-1 dense VALU fills layer-2 sparse-latency
// bubbles. LDS = P1(64K)+Phh(64K)+stM(32K) = 160 KB, 1024 thr, 4 waves/SIMD.
// Pih packed to global (PihG) by a setup kernel (R15 layout). Per-acc fma
// chain orders preserved -> bit-exact.

#define BB 65536
#define TT 24
#define NB 8  // batch elements per wave (two halves of 4)

typedef float pf2 __attribute__((ext_vector_type(2)));

__device__ __forceinline__ void pk_fma_wlo(pf2& acc, pf2 s, pf2 w) {
  asm("v_pk_fma_f32 %0, %1, %2, %0 op_sel:[0,0,0] op_sel_hi:[1,0,1]"
      : "+v"(acc) : "v"(s), "v"(w));
}
__device__ __forceinline__ void pk_fma_whi(pf2& acc, pf2 s, pf2 w) {
  asm("v_pk_fma_f32 %0, %1, %2, %0 op_sel:[0,1,0] op_sel_hi:[1,1,1]"
      : "+v"(acc) : "v"(s), "v"(w));
}

__device__ __forceinline__ float bcastf(float v, int l) {
  return __int_as_float(__builtin_amdgcn_readlane(__float_as_int(v), l));
}
__device__ __forceinline__ float sigm(float v) {
  return __fdividef(1.0f, 1.0f + __expf(-v));
}
__device__ __forceinline__ float tanh_fast(float v) {
  return fmaf(-2.0f, __fdividef(1.0f, __expf(2.0f * v) + 1.0f), 1.0f);
}
__device__ __forceinline__ float wsum(float v) {
#pragma unroll
  for (int o = 32; o > 0; o >>= 1) v += __shfl_xor(v, o);
  return v;
}

// Pack Wih2[256][64] (row q*64+j, col m) -> PihG[m*64+j] = float4 over q.
__global__ void snn_setup(const float* __restrict__ Wih2,
                          float* __restrict__ PihG) {
  int idx = blockIdx.x * blockDim.x + threadIdx.x;
  if (idx < 16384) {
    int k = idx >> 6, m = idx & 63;  // k = q*64 + j
    int q = k >> 6, j = k & 63;
    PihG[(m * 64 + j) * 4 + q] = Wih2[idx];
  }
}

__global__ __attribute__((amdgpu_waves_per_eu(4, 4))) __launch_bounds__(1024)
void snn_fused(
    const float* __restrict__ x, const float* __restrict__ Wih1,
    const float* __restrict__ Whh1, const float* __restrict__ bih1,
    const float* __restrict__ bhh1, const float* __restrict__ thr1p,
    const float* __restrict__ Whh2, const float* __restrict__ bih2,
    const float* __restrict__ bhh2, const float* __restrict__ thr2p,
    const float* __restrict__ Wout, const float* __restrict__ bout,
    const float4* __restrict__ PihG, float* __restrict__ out) {
  __shared__ float4 P1[64][64];      // 64 KB: layer-1 Whh packed per-lane
  __shared__ float4 Phh[64][64];     // 64 KB: layer-2 Whh packed per-lane
  __shared__ float stM[16][64][NB];  // 32 KB: per-wave broadcast strip (160 KB)
  int tid = threadIdx.x;
  for (int idx = tid; idx < 16384; idx += 1024) {
    int k = idx >> 6, m = idx & 63;
    ((float*)&P1[m][k & 63])[k >> 6] = Whh1[idx];
    ((float*)&Phh[m][k & 63])[k >> 6] = Whh2[idx];
  }
  __syncthreads();
  int lane = tid & 63, wave = tid >> 6;
  int wb = (blockIdx.x * 16 + wave) * NB;  // first batch of this wave
  float thr1 = thr1p[0], thr2 = thr2p[0];
  float b1q[4], wq[4], b2q[4];
#pragma unroll
  for (int q = 0; q < 4; q++) {
    b1q[q] = bih1[q * 64 + lane] + bhh1[q * 64 + lane];
    wq[q] = Wih1[q * 64 + lane];
    b2q[q] = bih2[q * 64 + lane] + bhh2[q * 64 + lane];
  }
  float syn1[NB], mem1[NB], syn2[NB], mem2[NB];
  unsigned sb8[NB];  // layer-2 spike history of THIS lane's neuron, bit t
#pragma unroll
  for (int b = 0; b < NB; b++) {
    syn1[b] = 0.0f; mem1[b] = 0.0f; syn2[b] = 0.0f; mem2[b] = 0.0f; sb8[b] = 0u;
  }

  for (int t = 0; t < TT; t++) {
    // ---------- layer 1 ----------
#pragma unroll
    for (int b = 0; b < NB; b++) stM[wave][lane][b] = mem1[b];
    unsigned long long mk[NB];  // layer-1 spike ballots (wave-uniform -> SGPR)
#pragma unroll
    for (int h = 0; h < 2; h++) {
      const int B0 = h * 4;
      pf2 a2[4][2];
#pragma unroll
      for (int p = 0; p < 2; p++) {
        float x0 = x[(wb + B0 + 2 * p) * TT + t];
        float x1 = x[(wb + B0 + 2 * p + 1) * TT + t];
#pragma unroll
        for (int q = 0; q < 4; q++)
          a2[q][p] = (pf2){fmaf(x0, wq[q], b1q[q]), fmaf(x1, wq[q], b1q[q])};
      }
#pragma unroll 8
      for (int m = 0; m < 64; m++) {
        float4 w = P1[m][lane];
        float4 sa = *(const float4*)&stM[wave][m][B0];
        pf2 s01 = {sa.x, sa.y}, s23 = {sa.z, sa.w};
        pf2 wxy = {w.x, w.y}, wzw = {w.z, w.w};
        pk_fma_wlo(a2[0][0], s01, wxy);
        pk_fma_whi(a2[1][0], s01, wxy);
        pk_fma_wlo(a2[2][0], s01, wzw);
        pk_fma_whi(a2[3][0], s01, wzw);
        pk_fma_wlo(a2[0][1], s23, wxy);
        pk_fma_whi(a2[1][1], s23, wxy);
        pk_fma_wlo(a2[2][1], s23, wzw);
        pk_fma_whi(a2[3][1], s23, wzw);
      }
#pragma unroll
      for (int j = 0; j < 4; j++) {
        int b = B0 + j, p = j >> 1;
        float aq0 = (j & 1) ? a2[0][p].y : a2[0][p].x;
        float aq1 = (j & 1) ? a2[1][p].y : a2[1][p].x;
        float aq2 = (j & 1) ? a2[2][p].y : a2[2][p].x;
        float aq3 = (j & 1) ? a2[3][p].y : a2[3][p].x;
        float ig = sigm(aq0), fg = sigm(aq1);
        float gg = tanh_fast(aq2), og = sigm(aq3);
        float sn = fmaf(fg, syn1[b], ig * gg);
        float rst = (mem1[b] > thr1) ? thr1 : 0.0f;  // reset uses OLD mem
        float mn = fmaf(og, tanh_fast(sn), -rst);
        syn1[b] = sn;
        mem1[b] = mn;
        mk[b] = __ballot(mn > thr1);  // uniform -> lives in SGPR pair
      }
      __builtin_amdgcn_sched_barrier(0);
    }
    // ---------- layer 2 (same t; masks in SGPRs, no memory) ----------
#pragma unroll
    for (int b = 0; b < NB; b++) stM[wave][lane][b] = mem2[b];
#pragma unroll
    for (int h = 0; h < 2; h++) {
      const int B0 = h * 4;
      pf2 a2[4][2];
#pragma unroll
      for (int q = 0; q < 4; q++) {
#pragma unroll
        for (int p = 0; p < 2; p++) a2[q][p] = (pf2){b2q[q], b2q[q]};
      }
      // dense hh half (LDS weights + broadcast state)
#pragma unroll 8
      for (int m = 0; m < 64; m++) {
        float4 wh = Phh[m][lane];
        float4 sa = *(const float4*)&stM[wave][m][B0];
        pf2 s01 = {sa.x, sa.y}, s23 = {sa.z, sa.w};
        pf2 wxy = {wh.x, wh.y}, wzw = {wh.z, wh.w};
        pk_fma_wlo(a2[0][0], s01, wxy);
        pk_fma_whi(a2[1][0], s01, wxy);
        pk_fma_wlo(a2[2][0], s01, wzw);
        pk_fma_whi(a2[3][0], s01, wzw);
        pk_fma_wlo(a2[0][1], s23, wxy);
        pk_fma_whi(a2[1][1], s23, wxy);
        pk_fma_wlo(a2[2][1], s23, wzw);
        pk_fma_whi(a2[3][1], s23, wzw);
      }
      // sparse ih half: global reads (VMEM), ascending-bit order preserved
#pragma unroll
      for (int j = 0; j < 4; j++) {
        int b = B0 + j, p = j >> 1;
        unsigned long long k = mk[b];
        while (__builtin_popcountll(k) >= 4) {
          int m0 = __builtin_ctzll(k); k &= k - 1;
          int m1 = __builtin_ctzll(k); k &= k - 1;
          int m2 = __builtin_ctzll(k); k &= k - 1;
          int m3 = __builtin_ctzll(k); k &= k - 1;
          float4 r0 = PihG[m0 * 64 + lane];
          float4 r1 = PihG[m1 * 64 + lane];
          float4 r2 = PihG[m2 * 64 + lane];
          float4 r3 = PihG[m3 * 64 + lane];
          if ((j & 1) == 0) {
            a2[0][p].x += r0.x; a2[1][p].x += r0.y; a2[2][p].x += r0.z; a2[3][p].x += r0.w;
            a2[0][p].x += r1.x; a2[1][p].x += r1.y; a2[2][p].x += r1.z; a2[3][p].x += r1.w;
            a2[0][p].x += r2.x; a2[1][p].x += r2.y; a2[2][p].x += r2.z; a2[3][p].x += r2.w;
            a2[0][p].x += r3.x; a2[1][p].x += r3.y; a2[2][p].x += r3.z; a2[3][p].x += r3.w;
          } else {
            a2[0][p].y += r0.x; a2[1][p].y += r0.y; a2[2][p].y += r0.z; a2[3][p].y += r0.w;
            a2[0][p].y += r1.x; a2[1][p].y += r1.y; a2[2][p].y += r1.z; a2[3][p].y += r1.w;
            a2[0][p].y += r2.x; a2[1][p].y += r2.y; a2[2][p].y += r2.z; a2[3][p].y += r2.w;
            a2[0][p].y += r3.x; a2[1][p].y += r3.y; a2[2][p].y += r3.z; a2[3][p].y += r3.w;
          }
        }
        while (k) {
          int m0 = __builtin_ctzll(k); k &= k - 1;
          float4 r0 = PihG[m0 * 64 + lane];
          if ((j & 1) == 0) {
            a2[0][p].x += r0.x; a2[1][p].x += r0.y; a2[2][p].x += r0.z; a2[3][p].x += r0.w;
          } else {
            a2[0][p].y += r0.x; a2[1][p].y += r0.y; a2[2][p].y += r0.z; a2[3][p].y += r0.w;
          }
        }
        float aq0 = (j & 1) ? a2[0][p].y : a2[0][p].x;
        float aq1 = (j & 1) ? a2[1][p].y : a2[1][p].x;
        float aq2 = (j & 1) ? a2[2][p].y : a2[2][p].x;
        float aq3 = (j & 1) ? a2[3][p].y : a2[3][p].x;
        float ig = sigm(aq0), fg = sigm(aq1);
        float gg = tanh_fast(aq2), og = sigm(aq3);
        float sn = fmaf(fg, syn2[b], ig * gg);
        float rst = (mem2[b] > thr2) ? thr2 : 0.0f;
        float mn = fmaf(og, tanh_fast(sn), -rst);
        syn2[b] = sn;
        mem2[b] = mn;
        sb8[b] |= (mn > thr2) ? (1u << t) : 0u;
      }
      __builtin_amdgcn_sched_barrier(0);
    }
  }

  // extra step: input = final mem1 (IN REGISTERS). readlane broadcast form,
  // interleaved per-m fma order preserved (identical to R14/R15 extra step).
  float acc[NB][4];
#pragma unroll
  for (int b = 0; b < NB; b++) {
#pragma unroll
    for (int q = 0; q < 4; q++) acc[b][q] = b2q[q];
  }
#pragma unroll 4
  for (int m = 0; m < 64; m++) {
    float4 wi = PihG[m * 64 + lane];
    float4 wh = Phh[m][lane];
#pragma unroll
    for (int b = 0; b < NB; b++) {
      float s1 = bcastf(mem1[b], m);
      float s2 = bcastf(mem2[b], m);
      acc[b][0] = fmaf(s1, wi.x, fmaf(s2, wh.x, acc[b][0]));
      acc[b][1] = fmaf(s1, wi.y, fmaf(s2, wh.y, acc[b][1]));
      acc[b][2] = fmaf(s1, wi.z, fmaf(s2, wh.z, acc[b][2]));
      acc[b][3] = fmaf(s1, wi.w, fmaf(s2, wh.w, acc[b][3]));
    }
  }
  // epilogue: p0/p1 from sb8 bits (same fmaf order), then extra-step terms.
  float p0[NB], p1[NB];
#pragma unroll
  for (int b = 0; b < NB; b++) { p0[b] = 0.0f; p1[b] = 0.0f; }
#pragma unroll 4
  for (int t = 0; t < TT; t++) {
    float w0 = Wout[t * 64 + lane];
    float w1 = Wout[1664 + t * 64 + lane];
#pragma unroll
    for (int b = 0; b < NB; b++) {
      float sf = ((sb8[b] >> t) & 1u) ? 1.0f : 0.0f;
      p0[b] = fmaf(sf, w0, p0[b]);
      p1[b] = fmaf(sf, w1, p1[b]);
    }
  }
  float wA0 = Wout[1536 + lane], wA1 = Wout[1664 + 1536 + lane];  // spk2_last
  float wB0 = Wout[1600 + lane], wB1 = Wout[1664 + 1600 + lane];  // mem2 final
  float bo0 = bout[0], bo1 = bout[1];
#pragma unroll
  for (int b = 0; b < NB; b++) {
    float ig = sigm(acc[b][0]), fg = sigm(acc[b][1]);
    float gg = tanh_fast(acc[b][2]), og = sigm(acc[b][3]);
    float sn = fmaf(fg, syn2[b], ig * gg);
    float rst = (mem2[b] > thr2) ? thr2 : 0.0f;
    float mn = fmaf(og, tanh_fast(sn), -rst);
    float sf = (mn > thr2) ? 1.0f : 0.0f;
    p0[b] = fmaf(sf, wA0, p0[b]);
    p1[b] = fmaf(sf, wA1, p1[b]);
    p0[b] = fmaf(mn, wB0, p0[b]);
    p1[b] = fmaf(mn, wB1, p1[b]);
  }
  // cross-lane reduce; wsum result is uniform, keep own lane's value.
  float vout = 0.0f;
#pragma unroll
  for (int b = 0; b < NB; b++) {
    float r0 = wsum(p0[b]);
    float r1 = wsum(p1[b]);
    if (lane == 2 * b) vout = r0;
    if (lane == 2 * b + 1) vout = r1;
  }
  if (lane < 2 * NB)
    out[(size_t)wb * 2 + lane] = vout + ((lane & 1) ? bo1 : bo0);
}

extern "C" void kernel_launch(void* const* d_in, const int* in_sizes, int n_in,
                              void* d_out, int out_size, void* d_ws, size_t ws_size,
                              hipStream_t stream) {
  const float* x = (const float*)d_in[0];
  const float* Wih1 = (const float*)d_in[1];
  const float* Whh1 = (const float*)d_in[2];
  const float* bih1 = (const float*)d_in[3];
  const float* bhh1 = (const float*)d_in[4];
  const float* thr1 = (const float*)d_in[5];
  const float* Wih2 = (const float*)d_in[6];
  const float* Whh2 = (const float*)d_in[7];
  const float* bih2 = (const float*)d_in[8];
  const float* bhh2 = (const float*)d_in[9];
  const float* thr2 = (const float*)d_in[10];
  const float* Wout = (const float*)d_in[11];
  const float* bout = (const float*)d_in[12];

  float* PihG = (float*)d_ws;  // 64 KB packed layer-2 input weights

  snn_setup<<<32, 512, 0, stream>>>(Wih2, PihG);
  snn_fused<<<BB / (16 * NB), 1024, 0, stream>>>(
      x, Wih1, Whh1, bih1, bhh1, thr1, Whh2, bih2, bhh2, thr2, Wout, bout,
      (const float4*)PihG, (float*)d_out);
}

// Round 17
// 1811.634 us; speedup vs baseline: 1.0326x; 1.0255x over previous
//
#include <hip/hip_runtime.h>
#include <cstdint>
#include <cstddef>

// SNN_53618371723788: 2-layer SLSTM, B=65536, T=24, H=64, fp32.
// R17: 8 waves/SIMD (2 co-resident 1024-thr blocks/CU). Ledger: only TLP
// (R7) and work removal (R9) ever moved duration; VALU-50% (R14), LDS-40%
// (R15), FETCH-73% (R16) all neutral -> pass2 is stall-bound at 4 waves/SIMD
// with LDS-pipe at ~26%. Occupancy was LDS-SIZE-capped (160 KB/block). Now
// each block uses 80 KB: stM 32 KB + 48/64 weight rows in LDS; rows 48..63
// from small packed global arrays (16 KB, L1-resident, same addr all waves).
// Sparse ih from PihG global (R15). m-order per acc unchanged -> bit-exact.

#define BB 65536
#define TT 24
#define NB 8  // batch elements per wave (two halves of 4)
#define MLDS 48  // weight rows resident in LDS; rows 48..63 from global

typedef float pf2 __attribute__((ext_vector_type(2)));

__device__ __forceinline__ void pk_fma_wlo(pf2& acc, pf2 s, pf2 w) {
  asm("v_pk_fma_f32 %0, %1, %2, %0 op_sel:[0,0,0] op_sel_hi:[1,0,1]"
      : "+v"(acc) : "v"(s), "v"(w));
}
__device__ __forceinline__ void pk_fma_whi(pf2& acc, pf2 s, pf2 w) {
  asm("v_pk_fma_f32 %0, %1, %2, %0 op_sel:[0,1,0] op_sel_hi:[1,1,1]"
      : "+v"(acc) : "v"(s), "v"(w));
}

__device__ __forceinline__ float bcastf(float v, int l) {
  return __int_as_float(__builtin_amdgcn_readlane(__float_as_int(v), l));
}
__device__ __forceinline__ float sigm(float v) {
  return __fdividef(1.0f, 1.0f + __expf(-v));
}
__device__ __forceinline__ float tanh_fast(float v) {
  return fmaf(-2.0f, __fdividef(1.0f, __expf(2.0f * v) + 1.0f), 1.0f);
}
__device__ __forceinline__ float wsum(float v) {
#pragma unroll
  for (int o = 32; o > 0; o >>= 1) v += __shfl_xor(v, o);
  return v;
}

// Pack: PihG[m*64+j] = float4 over q of Wih2 (full 64 KB);
// P1Gt / PhhGt = rows m>=48 only of Whh1 / Whh2 (16 KB each).
__global__ void snn_setup(const float* __restrict__ Whh1,
                          const float* __restrict__ Whh2,
                          const float* __restrict__ Wih2,
                          float* __restrict__ PihG, float* __restrict__ P1Gt,
                          float* __restrict__ PhhGt) {
  int idx = blockIdx.x * blockDim.x + threadIdx.x;
  if (idx < 16384) {
    int k = idx >> 6, m = idx & 63;  // k = q*64 + j
    int q = k >> 6, j = k & 63;
    PihG[(m * 64 + j) * 4 + q] = Wih2[idx];
    if (m >= MLDS) {
      P1Gt[((m - MLDS) * 64 + j) * 4 + q] = Whh1[idx];
      PhhGt[((m - MLDS) * 64 + j) * 4 + q] = Whh2[idx];
    }
  }
}

__global__ __launch_bounds__(1024) void snn_pass1(
    const float* __restrict__ x, const float* __restrict__ Wih1,
    const float* __restrict__ Whh1, const float* __restrict__ bih1,
    const float* __restrict__ bhh1, const float* __restrict__ thr1p,
    const float4* __restrict__ P1Gt,
    unsigned long long* __restrict__ spk_out, float* __restrict__ mem1_out) {
  __shared__ float4 P1[MLDS][64];    // 48 KB: rows 0..47
  __shared__ float stM[16][64][NB];  // 32 KB -> 80 KB total = 2 blocks/CU
  int tid = threadIdx.x;
  for (int idx = tid; idx < 16384; idx += 1024) {
    int k = idx >> 6, m = idx & 63;
    if (m < MLDS) ((float*)&P1[m][k & 63])[k >> 6] = Whh1[idx];
  }
  __syncthreads();
  int lane = tid & 63, wave = tid >> 6;
  int wb = (blockIdx.x * 16 + wave) * NB;  // first batch of this wave
  float thr1 = thr1p[0];
  float b1q[4], wq[4];
#pragma unroll
  for (int q = 0; q < 4; q++) {
    b1q[q] = bih1[q * 64 + lane] + bhh1[q * 64 + lane];
    wq[q] = Wih1[q * 64 + lane];
  }
  float syn[NB], mem[NB];
#pragma unroll
  for (int b = 0; b < NB; b++) { syn[b] = 0.0f; mem[b] = 0.0f; }

  for (int t = 0; t < TT; t++) {
#pragma unroll
    for (int b = 0; b < NB; b++) stM[wave][lane][b] = mem[b];
    unsigned long long myspk = 0;  // lane b keeps batch b's ballot
#pragma unroll
    for (int h = 0; h < 2; h++) {
      const int B0 = h * 4;
      pf2 a2[4][2];
#pragma unroll
      for (int p = 0; p < 2; p++) {
        float x0 = x[(wb + B0 + 2 * p) * TT + t];
        float x1 = x[(wb + B0 + 2 * p + 1) * TT + t];
#pragma unroll
        for (int q = 0; q < 4; q++)
          a2[q][p] = (pf2){fmaf(x0, wq[q], b1q[q]), fmaf(x1, wq[q], b1q[q])};
      }
      // m = 0..47 from LDS (same sequence as before -> bit-exact)
#pragma unroll 8
      for (int m = 0; m < MLDS; m++) {
        float4 w = P1[m][lane];
        float4 sa = *(const float4*)&stM[wave][m][B0];
        pf2 s01 = {sa.x, sa.y}, s23 = {sa.z, sa.w};
        pf2 wxy = {w.x, w.y}, wzw = {w.z, w.w};
        pk_fma_wlo(a2[0][0], s01, wxy);
        pk_fma_whi(a2[1][0], s01, wxy);
        pk_fma_wlo(a2[2][0], s01, wzw);
        pk_fma_whi(a2[3][0], s01, wzw);
        pk_fma_wlo(a2[0][1], s23, wxy);
        pk_fma_whi(a2[1][1], s23, wxy);
        pk_fma_wlo(a2[2][1], s23, wzw);
        pk_fma_whi(a2[3][1], s23, wzw);
      }
      // m = 48..63 from global (16 KB, L1-resident; VMEM pipe)
#pragma unroll 8
      for (int m = MLDS; m < 64; m++) {
        float4 w = P1Gt[(m - MLDS) * 64 + lane];
        float4 sa = *(const float4*)&stM[wave][m][B0];
        pf2 s01 = {sa.x, sa.y}, s23 = {sa.z, sa.w};
        pf2 wxy = {w.x, w.y}, wzw = {w.z, w.w};
        pk_fma_wlo(a2[0][0], s01, wxy);
        pk_fma_whi(a2[1][0], s01, wxy);
        pk_fma_wlo(a2[2][0], s01, wzw);
        pk_fma_whi(a2[3][0], s01, wzw);
        pk_fma_wlo(a2[0][1], s23, wxy);
        pk_fma_whi(a2[1][1], s23, wxy);
        pk_fma_wlo(a2[2][1], s23, wzw);
        pk_fma_whi(a2[3][1], s23, wzw);
      }
#pragma unroll
      for (int j = 0; j < 4; j++) {
        int b = B0 + j, p = j >> 1;
        float aq0 = (j & 1) ? a2[0][p].y : a2[0][p].x;
        float aq1 = (j & 1) ? a2[1][p].y : a2[1][p].x;
        float aq2 = (j & 1) ? a2[2][p].y : a2[2][p].x;
        float aq3 = (j & 1) ? a2[3][p].y : a2[3][p].x;
        float ig = sigm(aq0), fg = sigm(aq1);
        float gg = tanh_fast(aq2), og = sigm(aq3);
        float sn = fmaf(fg, syn[b], ig * gg);
        float rst = (mem[b] > thr1) ? thr1 : 0.0f;  // reset uses OLD mem
        float mn = fmaf(og, tanh_fast(sn), -rst);
        syn[b] = sn;
        mem[b] = mn;
        unsigned long long msk = __ballot(mn > thr1);  // wave-uniform
        if (lane == b) myspk = msk;
      }
      __builtin_amdgcn_sched_barrier(0);
    }
    if (lane < NB)
      spk_out[(size_t)t * BB + wb + lane] = myspk;
  }
#pragma unroll
  for (int b = 0; b < NB; b++)
    mem1_out[(size_t)(wb + b) * 64 + lane] = mem[b];
}

__global__ __launch_bounds__(1024) void snn_pass2(
    const float* __restrict__ Wih2, const float* __restrict__ Whh2,
    const float* __restrict__ bih2, const float* __restrict__ bhh2,
    const float* __restrict__ thr2p, const float* __restrict__ Wout,
    const float* __restrict__ bout, const float4* __restrict__ PihG,
    const float4* __restrict__ PhhGt,
    const unsigned long long* __restrict__ spk_in,
    const float* __restrict__ mem1_in, float* __restrict__ out) {
  __shared__ float4 Phh[MLDS][64];   // 48 KB: rows 0..47
  __shared__ float stM[16][64][NB];  // 32 KB -> 80 KB total = 2 blocks/CU
  int tid = threadIdx.x;
  for (int idx = tid; idx < 16384; idx += 1024) {
    int k = idx >> 6, m = idx & 63;
    if (m < MLDS) ((float*)&Phh[m][k & 63])[k >> 6] = Whh2[idx];
  }
  __syncthreads();
  int lane = tid & 63, wave = tid >> 6;
  int wb = (blockIdx.x * 16 + wave) * NB;
  float thr2 = thr2p[0];
  float b2q[4];
#pragma unroll
  for (int q = 0; q < 4; q++) b2q[q] = bih2[q * 64 + lane] + bhh2[q * 64 + lane];
  float syn[NB], mem[NB];
  unsigned sb8[NB];  // layer-2 spike history of THIS lane's neuron, bit t
#pragma unroll
  for (int b = 0; b < NB; b++) { syn[b] = 0.0f; mem[b] = 0.0f; sb8[b] = 0u; }

  for (int t = 0; t < TT; t++) {
    unsigned long long mk[NB];
#pragma unroll
    for (int b = 0; b < NB; b++) {
      unsigned long long v = spk_in[(size_t)t * BB + wb + b];
      unsigned lo = __builtin_amdgcn_readfirstlane((unsigned)v);
      unsigned hi = __builtin_amdgcn_readfirstlane((unsigned)(v >> 32));
      mk[b] = ((unsigned long long)hi << 32) | (unsigned long long)lo;
    }
#pragma unroll
    for (int b = 0; b < NB; b++) stM[wave][lane][b] = mem[b];
#pragma unroll
    for (int h = 0; h < 2; h++) {
      const int B0 = h * 4;
      pf2 a2[4][2];
#pragma unroll
      for (int q = 0; q < 4; q++) {
#pragma unroll
        for (int p = 0; p < 2; p++) a2[q][p] = (pf2){b2q[q], b2q[q]};
      }
      // dense hh: m 0..47 LDS, 48..63 global (order preserved)
#pragma unroll 8
      for (int m = 0; m < MLDS; m++) {
        float4 wh = Phh[m][lane];
        float4 sa = *(const float4*)&stM[wave][m][B0];
        pf2 s01 = {sa.x, sa.y}, s23 = {sa.z, sa.w};
        pf2 wxy = {wh.x, wh.y}, wzw = {wh.z, wh.w};
        pk_fma_wlo(a2[0][0], s01, wxy);
        pk_fma_whi(a2[1][0], s01, wxy);
        pk_fma_wlo(a2[2][0], s01, wzw);
        pk_fma_whi(a2[3][0], s01, wzw);
        pk_fma_wlo(a2[0][1], s23, wxy);
        pk_fma_whi(a2[1][1], s23, wxy);
        pk_fma_wlo(a2[2][1], s23, wzw);
        pk_fma_whi(a2[3][1], s23, wzw);
      }
#pragma unroll 8
      for (int m = MLDS; m < 64; m++) {
        float4 wh = PhhGt[(m - MLDS) * 64 + lane];
        float4 sa = *(const float4*)&stM[wave][m][B0];
        pf2 s01 = {sa.x, sa.y}, s23 = {sa.z, sa.w};
        pf2 wxy = {wh.x, wh.y}, wzw = {wh.z, wh.w};
        pk_fma_wlo(a2[0][0], s01, wxy);
        pk_fma_whi(a2[1][0], s01, wxy);
        pk_fma_wlo(a2[2][0], s01, wzw);
        pk_fma_whi(a2[3][0], s01, wzw);
        pk_fma_wlo(a2[0][1], s23, wxy);
        pk_fma_whi(a2[1][1], s23, wxy);
        pk_fma_wlo(a2[2][1], s23, wzw);
        pk_fma_whi(a2[3][1], s23, wzw);
      }
      // sparse ih: global reads, ascending-bit order preserved
#pragma unroll
      for (int j = 0; j < 4; j++) {
        int b = B0 + j, p = j >> 1;
        unsigned long long k = mk[b];
        while (__builtin_popcountll(k) >= 4) {
          int m0 = __builtin_ctzll(k); k &= k - 1;
          int m1 = __builtin_ctzll(k); k &= k - 1;
          int m2 = __builtin_ctzll(k); k &= k - 1;
          int m3 = __builtin_ctzll(k); k &= k - 1;
          float4 r0 = PihG[m0 * 64 + lane];
          float4 r1 = PihG[m1 * 64 + lane];
          float4 r2 = PihG[m2 * 64 + lane];
          float4 r3 = PihG[m3 * 64 + lane];
          if ((j & 1) == 0) {
            a2[0][p].x += r0.x; a2[1][p].x += r0.y; a2[2][p].x += r0.z; a2[3][p].x += r0.w;
            a2[0][p].x += r1.x; a2[1][p].x += r1.y; a2[2][p].x += r1.z; a2[3][p].x += r1.w;
            a2[0][p].x += r2.x; a2[1][p].x += r2.y; a2[2][p].x += r2.z; a2[3][p].x += r2.w;
            a2[0][p].x += r3.x; a2[1][p].x += r3.y; a2[2][p].x += r3.z; a2[3][p].x += r3.w;
          } else {
            a2[0][p].y += r0.x; a2[1][p].y += r0.y; a2[2][p].y += r0.z; a2[3][p].y += r0.w;
            a2[0][p].y += r1.x; a2[1][p].y += r1.y; a2[2][p].y += r1.z; a2[3][p].y += r1.w;
            a2[0][p].y += r2.x; a2[1][p].y += r2.y; a2[2][p].y += r2.z; a2[3][p].y += r2.w;
            a2[0][p].y += r3.x; a2[1][p].y += r3.y; a2[2][p].y += r3.z; a2[3][p].y += r3.w;
          }
        }
        while (k) {
          int m0 = __builtin_ctzll(k); k &= k - 1;
          float4 r0 = PihG[m0 * 64 + lane];
          if ((j & 1) == 0) {
            a2[0][p].x += r0.x; a2[1][p].x += r0.y; a2[2][p].x += r0.z; a2[3][p].x += r0.w;
          } else {
            a2[0][p].y += r0.x; a2[1][p].y += r0.y; a2[2][p].y += r0.z; a2[3][p].y += r0.w;
          }
        }
        float aq0 = (j & 1) ? a2[0][p].y : a2[0][p].x;
        float aq1 = (j & 1) ? a2[1][p].y : a2[1][p].x;
        float aq2 = (j & 1) ? a2[2][p].y : a2[2][p].x;
        float aq3 = (j & 1) ? a2[3][p].y : a2[3][p].x;
        float ig = sigm(aq0), fg = sigm(aq1);
        float gg = tanh_fast(aq2), og = sigm(aq3);
        float sn = fmaf(fg, syn[b], ig * gg);
        float rst = (mem[b] > thr2) ? thr2 : 0.0f;
        float mn = fmaf(og, tanh_fast(sn), -rst);
        syn[b] = sn;
        mem[b] = mn;
        sb8[b] |= (mn > thr2) ? (1u << t) : 0u;
      }
      __builtin_amdgcn_sched_barrier(0);
    }
  }

  // extra step: input = final mem1 (dense); Pih global, Phh split LDS/global.
  float m1[NB];
#pragma unroll
  for (int b = 0; b < NB; b++) m1[b] = mem1_in[(size_t)(wb + b) * 64 + lane];
  float acc[NB][4];
#pragma unroll
  for (int b = 0; b < NB; b++) {
#pragma unroll
    for (int q = 0; q < 4; q++) acc[b][q] = b2q[q];
  }
#pragma unroll 4
  for (int m = 0; m < 64; m++) {
    float4 wi = PihG[m * 64 + lane];
    float4 wh = (m < MLDS) ? Phh[m][lane] : PhhGt[(m - MLDS) * 64 + lane];
#pragma unroll
    for (int b = 0; b < NB; b++) {
      float s1 = bcastf(m1[b], m);
      float s2 = bcastf(mem[b], m);
      acc[b][0] = fmaf(s1, wi.x, fmaf(s2, wh.x, acc[b][0]));
      acc[b][1] = fmaf(s1, wi.y, fmaf(s2, wh.y, acc[b][1]));
      acc[b][2] = fmaf(s1, wi.z, fmaf(s2, wh.z, acc[b][2]));
      acc[b][3] = fmaf(s1, wi.w, fmaf(s2, wh.w, acc[b][3]));
    }
  }
  // epilogue: replay p0/p1 from sb8 bits (same fmaf order).
  float p0[NB], p1[NB];
#pragma unroll
  for (int b = 0; b < NB; b++) { p0[b] = 0.0f; p1[b] = 0.0f; }
#pragma unroll 4
  for (int t = 0; t < TT; t++) {
    float w0 = Wout[t * 64 + lane];
    float w1 = Wout[1664 + t * 64 + lane];
#pragma unroll
    for (int b = 0; b < NB; b++) {
      float sf = ((sb8[b] >> t) & 1u) ? 1.0f : 0.0f;
      p0[b] = fmaf(sf, w0, p0[b]);
      p1[b] = fmaf(sf, w1, p1[b]);
    }
  }
  float wA0 = Wout[1536 + lane], wA1 = Wout[1664 + 1536 + lane];  // spk2_last
  float wB0 = Wout[1600 + lane], wB1 = Wout[1664 + 1600 + lane];  // mem2 final
  float bo0 = bout[0], bo1 = bout[1];
#pragma unroll
  for (int b = 0; b < NB; b++) {
    float ig = sigm(acc[b][0]), fg = sigm(acc[b][1]);
    float gg = tanh_fast(acc[b][2]), og = sigm(acc[b][3]);
    float sn = fmaf(fg, syn[b], ig * gg);
    float rst = (mem[b] > thr2) ? thr2 : 0.0f;
    float mn = fmaf(og, tanh_fast(sn), -rst);
    float sf = (mn > thr2) ? 1.0f : 0.0f;
    p0[b] = fmaf(sf, wA0, p0[b]);
    p1[b] = fmaf(sf, wA1, p1[b]);
    p0[b] = fmaf(mn, wB0, p0[b]);
    p1[b] = fmaf(mn, wB1, p1[b]);
  }
  float vout = 0.0f;
#pragma unroll
  for (int b = 0; b < NB; b++) {
    float r0 = wsum(p0[b]);
    float r1 = wsum(p1[b]);
    if (lane == 2 * b) vout = r0;
    if (lane == 2 * b + 1) vout = r1;
  }
  if (lane < 2 * NB)
    out[(size_t)wb * 2 + lane] = vout + ((lane & 1) ? bo1 : bo0);
}

extern "C" void kernel_launch(void* const* d_in, const int* in_sizes, int n_in,
                              void* d_out, int out_size, void* d_ws, size_t ws_size,
                              hipStream_t stream) {
  const float* x = (const float*)d_in[0];
  const float* Wih1 = (const float*)d_in[1];
  const float* Whh1 = (const float*)d_in[2];
  const float* bih1 = (const float*)d_in[3];
  const float* bhh1 = (const float*)d_in[4];
  const float* thr1 = (const float*)d_in[5];
  const float* Wih2 = (const float*)d_in[6];
  const float* Whh2 = (const float*)d_in[7];
  const float* bih2 = (const float*)d_in[8];
  const float* bhh2 = (const float*)d_in[9];
  const float* thr2 = (const float*)d_in[10];
  const float* Wout = (const float*)d_in[11];
  const float* bout = (const float*)d_in[12];

  unsigned long long* spk = (unsigned long long*)d_ws;           // 12.58 MB
  float* mem1 = (float*)((char*)d_ws + (size_t)TT * BB * 8);     // 16.78 MB
  float* PihG = (float*)((char*)d_ws + (size_t)TT * BB * 8 + (size_t)BB * 64 * 4);
  float* P1Gt = PihG + 16384;   // 16 KB (rows 48..63 of Whh1)
  float* PhhGt = P1Gt + 4096;   // 16 KB (rows 48..63 of Whh2)

  snn_setup<<<32, 512, 0, stream>>>(Whh1, Whh2, Wih2, PihG, P1Gt, PhhGt);
  snn_pass1<<<BB / (16 * NB), 1024, 0, stream>>>(
      x, Wih1, Whh1, bih1, bhh1, thr1, (const float4*)P1Gt, spk, mem1);
  snn_pass2<<<BB / (16 * NB), 1024, 0, stream>>>(
      Wih2, Whh2, bih2, bhh2, thr2, Wout, bout, (const float4*)PihG,
      (const float4*)PhhGt, spk, mem1, (float*)d_out);
}